// Round 1
// baseline (168.617 us; speedup 1.0000x reference)
//
#include <hip/hip_runtime.h>
#include <hip/hip_bf16.h>
#include <cstdint>
#include <math.h>

// Shapes: B=256, P=128, K=512, HE=1024, HF=512 (2HF=1024), D=2560, HID=64
// Outputs: embeddings (256,1,1536) then weights (256,128), fp32, flat-concat.

typedef __bf16 bf16;
typedef __attribute__((ext_vector_type(8))) __bf16 bf16x8;
typedef __attribute__((ext_vector_type(4))) __bf16 bf16x4;
typedef __attribute__((ext_vector_type(4))) float f32x4;

#define NB 256
#define NP 128
#define NK 512
#define SKLD 520   // keys LDS row stride in bf16 elems: 520*2B=1040B -> 4-bank shift/row, 2-way alias (free)
#define SK_BYTES (NP * SKLD * 2)                  // 133120
#define SMEM_BYTES (SK_BYTES + 128*4 + 128*4 + 64*4 + 64*4)  // +scores+wts+proj+w2 = 134656

// ---------------- Kernel A: proj GEMM + W1k repack ----------------
// blocks 0..31 : proj[b,h] for b in [8j,8j+8): each block reads W1qf (512KB) once.
//   thread: h = t&63, g = t>>6 owns d-range [512g, 512g+512), 8 batches reg-blocked.
// blocks 32..47: W1kT[h][k] = bf16(W1[k*64+h]) (transposed, K-major for MFMA B-frags)
__global__ __launch_bounds__(256) void prep_kernel(
    const float* __restrict__ query, const float* __restrict__ frame,
    const float* __restrict__ W1, bf16* __restrict__ w1kt,
    float* __restrict__ proj)
{
    const int blk = blockIdx.x;
    const int t = threadIdx.x;
    if (blk < 32) {
        __shared__ float part[4][8][64];
        const int h = t & 63;
        const int g = t >> 6;
        const int b0 = blk * 8;
        // d in [g*512, g*512+512): g<2 -> query (W1 row 512+d), g>=2 -> frame
        const float* src = (g < 2) ? (query + g * 512) : (frame + (g - 2) * 512);
        const float* wrow = W1 + (size_t)(512 + g * 512) * 64 + h;
        float acc[8];
#pragma unroll
        for (int bb = 0; bb < 8; bb++) acc[bb] = 0.f;
#pragma unroll 4
        for (int dd = 0; dd < 512; dd++) {
            const float wv = wrow[(size_t)dd * 64];
#pragma unroll
            for (int bb = 0; bb < 8; bb++)
                acc[bb] += src[(size_t)(b0 + bb) * 1024 + dd] * wv;
        }
#pragma unroll
        for (int bb = 0; bb < 8; bb++) part[g][bb][h] = acc[bb];
        __syncthreads();
        for (int o = t; o < 512; o += 256) {
            const int bb = o >> 6, h2 = o & 63;
            proj[(size_t)(b0 + bb) * 64 + h2] =
                part[0][bb][h2] + part[1][bb][h2] + part[2][bb][h2] + part[3][bb][h2];
        }
    } else {
        const int jj = blk - 32;             // 0..15
        const int h = jj * 4 + (t >> 6);     // 0..63
        const int kbase = t & 63;
#pragma unroll
        for (int i = 0; i < 8; i++) {
            const int k = kbase + 64 * i;
            w1kt[(size_t)h * 512 + k] = (bf16)W1[(size_t)k * 64 + h];
        }
    }
}

// ---------------- Kernel B: fused attention, one block per batch ----------------
__global__ __launch_bounds__(256) void attn_kernel(
    const float* __restrict__ keys, const float* __restrict__ frame,
    const int* __restrict__ mask, const float* __restrict__ W2,
    const bf16* __restrict__ w1kt, const float* __restrict__ proj,
    float* __restrict__ out)
{
    extern __shared__ char smem[];
    bf16* sk       = (bf16*)smem;                       // [128][520] bf16
    float* scores  = (float*)(smem + SK_BYTES);         // [128]
    float* wts     = scores + 128;                      // [128]
    float* projl   = wts + 128;                         // [64]
    float* w2l     = projl + 64;                        // [64]

    const int b = blockIdx.x;
    const int t = threadIdx.x;

    if (t < 64) projl[t] = proj[(size_t)b * 64 + t];
    else if (t < 128) w2l[t - 64] = W2[t - 64];

    // ---- stage keys[b] (128x512 fp32) -> LDS bf16, coalesced 1KB/wave-instr ----
    const float* kb = keys + (size_t)b * (NP * NK);
    {
        const int rowadd = (t >> 7);          // 0/1
        const int c0 = (t & 127) * 4;
#pragma unroll 4
        for (int i = 0; i < 64; i++) {
            const float4 v = *(const float4*)(kb + (size_t)i * 1024 + t * 4);
            bf16x4 bv;
            bv[0] = (bf16)v.x; bv[1] = (bf16)v.y; bv[2] = (bf16)v.z; bv[3] = (bf16)v.w;
            *(bf16x4*)(sk + (2 * i + rowadd) * SKLD + c0) = bv;
        }
    }
    __syncthreads();

    // ---- GEMM: C[p][h] = keys_bf16 @ W1k_bf16 via mfma_f32_16x16x32_bf16 ----
    // wave w owns p in [32w, 32w+32) (2 M-tiles), all 4 N-tiles (h=0..63)
    const int w = t >> 6;
    const int lane = t & 63;
    const int m = lane & 15;       // A row within tile / B col (h) within tile / C col
    const int q = lane >> 4;       // k-quad; C row = q*4 + reg
    const int pw = w * 32;

    f32x4 acc[2][4];
#pragma unroll
    for (int a = 0; a < 2; a++)
#pragma unroll
        for (int n = 0; n < 4; n++) acc[a][n] = (f32x4){0.f, 0.f, 0.f, 0.f};

    for (int kk = 0; kk < 16; kk++) {
        const int k0 = kk * 32 + q * 8;
        const bf16x8 A0 = *(const bf16x8*)(sk + (pw + m) * SKLD + k0);
        const bf16x8 A1 = *(const bf16x8*)(sk + (pw + 16 + m) * SKLD + k0);
#pragma unroll
        for (int nt = 0; nt < 4; nt++) {
            const bf16x8 Bf = *(const bf16x8*)(w1kt + (size_t)(nt * 16 + m) * 512 + k0);
            acc[0][nt] = __builtin_amdgcn_mfma_f32_16x16x32_bf16(A0, Bf, acc[0][nt], 0, 0, 0);
            acc[1][nt] = __builtin_amdgcn_mfma_f32_16x16x32_bf16(A1, Bf, acc[1][nt], 0, 0, 0);
        }
    }

    // ---- epilogue: score[p] = sum_h relu(C[p][h]+proj[h]) * W2[h] ----
#pragma unroll
    for (int mt = 0; mt < 2; mt++) {
        float p0 = 0.f, p1 = 0.f, p2 = 0.f, p3 = 0.f;
#pragma unroll
        for (int nt = 0; nt < 4; nt++) {
            const int h = nt * 16 + m;
            const float pr = projl[h];
            const float w2v = w2l[h];
            const f32x4 c = acc[mt][nt];
            p0 += fmaxf(c[0] + pr, 0.f) * w2v;
            p1 += fmaxf(c[1] + pr, 0.f) * w2v;
            p2 += fmaxf(c[2] + pr, 0.f) * w2v;
            p3 += fmaxf(c[3] + pr, 0.f) * w2v;
        }
#pragma unroll
        for (int off = 1; off < 16; off <<= 1) {
            p0 += __shfl_xor(p0, off);
            p1 += __shfl_xor(p1, off);
            p2 += __shfl_xor(p2, off);
            p3 += __shfl_xor(p3, off);
        }
        if (m == 0) {
            const int pbase = pw + mt * 16 + q * 4;
            scores[pbase + 0] = p0; scores[pbase + 1] = p1;
            scores[pbase + 2] = p2; scores[pbase + 3] = p3;
        }
    }
    __syncthreads();

    // ---- masked softmax over 128 scores (wave 0), write weights ----
    if (w == 0) {
        const int pa = lane, pb = lane + 64;
        float s0 = (mask[b * 128 + pa] == 0) ? -INFINITY : scores[pa];
        float s1 = (mask[b * 128 + pb] == 0) ? -INFINITY : scores[pb];
        float mx = fmaxf(s0, s1);
#pragma unroll
        for (int off = 32; off; off >>= 1) mx = fmaxf(mx, __shfl_xor(mx, off));
        float e0 = __expf(s0 - mx), e1 = __expf(s1 - mx);
        float sum = e0 + e1;
#pragma unroll
        for (int off = 32; off; off >>= 1) sum += __shfl_xor(sum, off);
        const float inv = 1.0f / sum;
        e0 *= inv; e1 *= inv;
        wts[pa] = e0; wts[pb] = e1;
        float* wout = out + (size_t)NB * 1536;
        wout[b * 128 + pa] = e0;
        wout[b * 128 + pb] = e1;
    }
    __syncthreads();

    // ---- context[k] = sum_p w[p]*keys[p][k]; thread owns cols 2t, 2t+1 ----
    {
        float a0 = 0.f, a1 = 0.f;
        const int c = 2 * t;
#pragma unroll 4
        for (int p = 0; p < 128; p++) {
            const float wv = wts[p];
            const uint32_t uv = *(const uint32_t*)(sk + p * SKLD + c);
            const float f0 = __uint_as_float(uv << 16);
            const float f1 = __uint_as_float(uv & 0xffff0000u);
            a0 += wv * f0;
            a1 += wv * f1;
        }
        out[(size_t)b * 1536 + c] = a0;
        out[(size_t)b * 1536 + c + 1] = a1;
    }
    // ---- frame passthrough: embeddings[:, 512:1536] = frameLSTM_h ----
    {
        const float4 fv = *(const float4*)(frame + (size_t)b * 1024 + t * 4);
        *(float4*)(out + (size_t)b * 1536 + 512 + t * 4) = fv;
    }
}

extern "C" void kernel_launch(void* const* d_in, const int* in_sizes, int n_in,
                              void* d_out, int out_size, void* d_ws, size_t ws_size,
                              hipStream_t stream) {
    const float* query = (const float*)d_in[0];
    const float* keys  = (const float*)d_in[1];
    const float* frame = (const float*)d_in[2];
    const int*   mask  = (const int*)d_in[3];
    const float* W1    = (const float*)d_in[4];
    const float* W2    = (const float*)d_in[5];
    float* out = (float*)d_out;

    // ws layout: [0,64KB) W1kT bf16 [64][512]; [64KB,128KB) proj fp32 [256][64]
    bf16*  w1kt = (bf16*)d_ws;
    float* proj = (float*)((char*)d_ws + 65536);

    hipFuncSetAttribute((const void*)attn_kernel,
                        hipFuncAttributeMaxDynamicSharedMemorySize, SMEM_BYTES);

    prep_kernel<<<48, 256, 0, stream>>>(query, frame, W1, w1kt, proj);
    attn_kernel<<<256, 256, SMEM_BYTES, stream>>>(keys, frame, mask, W2, w1kt, proj, out);
}

// Round 2
// 139.992 us; speedup vs baseline: 1.2045x; 1.2045x over previous
//
#include <hip/hip_runtime.h>
#include <hip/hip_bf16.h>
#include <cstdint>
#include <math.h>

// Shapes: B=256, P=128, K=512, HE=1024, HF=512 (2HF=1024), D=2560, HID=64
// Outputs: embeddings (256,1,1536) then weights (256,128), fp32, flat-concat.

typedef __bf16 bf16;
typedef __attribute__((ext_vector_type(8))) __bf16 bf16x8;
typedef __attribute__((ext_vector_type(4))) __bf16 bf16x4;
typedef __attribute__((ext_vector_type(4))) float f32x4;

#define NB 256
#define NP 128
#define NK 512
#define SKLD 520   // keys LDS row stride in bf16 elems: 520*2B=1040B -> 4-bank shift/row, 2-way alias (free)
#define SK_BYTES (NP * SKLD * 2)                  // 133120
#define SMEM_BYTES (SK_BYTES + 128*4 + 128*4 + 64*4 + 64*4)  // +scores+wts+proj+w2 = 134656

// ---------------- Kernel A: proj GEMV (1 block/batch) + W1k repack ----------------
// blocks 0..255 : proj[b,:] — 256 threads: h=t&63, g=t>>6 owns d-range [512g,512g+512)
//   R0 post-mortem: 48-block version was load-latency-bound (50 µs warm, VALUBusy 1.8%).
//   256 blocks + 1 batch/thread cuts serial depth 8x and spreads latency across CUs.
// blocks 256..271: W1kT[h][k] = bf16(W1[k*64+h]) via LDS transpose (coalesced both sides)
__global__ __launch_bounds__(256) void prep_kernel(
    const float* __restrict__ query, const float* __restrict__ frame,
    const float* __restrict__ W1, bf16* __restrict__ w1kt,
    float* __restrict__ proj)
{
    const int blk = blockIdx.x;
    const int t = threadIdx.x;
    if (blk < 256) {
        __shared__ float part[4][64];
        const int b = blk;
        const int h = t & 63;
        const int g = t >> 6;
        // d in [g*512, g*512+512): g<2 -> query (W1 row 512+d), g>=2 -> frame
        const float* src = (g < 2) ? (query + (size_t)b * 1024 + g * 512)
                                   : (frame + (size_t)b * 1024 + (g - 2) * 512);
        const float* wrow = W1 + (size_t)(512 + g * 512) * 64 + h;
        float acc = 0.f;
#pragma unroll 8
        for (int dd = 0; dd < 512; dd++)
            acc += src[dd] * wrow[(size_t)dd * 64];
        part[g][h] = acc;
        __syncthreads();
        if (t < 64)
            proj[(size_t)b * 64 + t] = part[0][t] + part[1][t] + part[2][t] + part[3][t];
    } else {
        // repack: 16 blocks, block j handles k-rows [32j, 32j+32)
        __shared__ float s[32][65];
        const int j = blk - 256;
        const int k0 = j * 32;
#pragma unroll
        for (int i = 0; i < 8; i++) {
            const int idx = t + 256 * i;          // 0..2047
            const int k = idx >> 6, h = idx & 63;
            s[k][h] = W1[(size_t)(k0 + k) * 64 + h];
        }
        __syncthreads();
#pragma unroll
        for (int i = 0; i < 8; i++) {
            const int idx = t + 256 * i;
            const int h = idx >> 5, kk = idx & 31;
            w1kt[(size_t)h * 512 + k0 + kk] = (bf16)s[kk][h];
        }
    }
}

// ---------------- Kernel B: fused attention, one block per batch ----------------
__global__ __launch_bounds__(256) void attn_kernel(
    const float* __restrict__ keys, const float* __restrict__ frame,
    const int* __restrict__ mask, const float* __restrict__ W2,
    const bf16* __restrict__ w1kt, const float* __restrict__ proj,
    float* __restrict__ out)
{
    extern __shared__ char smem[];
    bf16* sk       = (bf16*)smem;                       // [128][520] bf16
    float* scores  = (float*)(smem + SK_BYTES);         // [128]
    float* wts     = scores + 128;                      // [128]
    float* projl   = wts + 128;                         // [64]
    float* w2l     = projl + 64;                        // [64]

    const int b = blockIdx.x;
    const int t = threadIdx.x;

    if (t < 64) projl[t] = proj[(size_t)b * 64 + t];
    else if (t < 128) w2l[t - 64] = W2[t - 64];

    // ---- stage keys[b] (128x512 fp32) -> LDS bf16, coalesced 1KB/wave-instr ----
    const float* kb = keys + (size_t)b * (NP * NK);
    {
        const int rowadd = (t >> 7);          // 0/1
        const int c0 = (t & 127) * 4;
#pragma unroll 4
        for (int i = 0; i < 64; i++) {
            const float4 v = *(const float4*)(kb + (size_t)i * 1024 + t * 4);
            bf16x4 bv;
            bv[0] = (bf16)v.x; bv[1] = (bf16)v.y; bv[2] = (bf16)v.z; bv[3] = (bf16)v.w;
            *(bf16x4*)(sk + (2 * i + rowadd) * SKLD + c0) = bv;
        }
    }
    __syncthreads();

    // ---- GEMM: C[p][h] = keys_bf16 @ W1k_bf16 via mfma_f32_16x16x32_bf16 ----
    // wave w owns p in [32w, 32w+32) (2 M-tiles), all 4 N-tiles (h=0..63)
    const int w = t >> 6;
    const int lane = t & 63;
    const int m = lane & 15;       // A row within tile / B col (h) within tile / C col
    const int q = lane >> 4;       // k-quad; C row = q*4 + reg
    const int pw = w * 32;

    f32x4 acc[2][4];
#pragma unroll
    for (int a = 0; a < 2; a++)
#pragma unroll
        for (int n = 0; n < 4; n++) acc[a][n] = (f32x4){0.f, 0.f, 0.f, 0.f};

    for (int kk = 0; kk < 16; kk++) {
        const int k0 = kk * 32 + q * 8;
        const bf16x8 A0 = *(const bf16x8*)(sk + (pw + m) * SKLD + k0);
        const bf16x8 A1 = *(const bf16x8*)(sk + (pw + 16 + m) * SKLD + k0);
#pragma unroll
        for (int nt = 0; nt < 4; nt++) {
            const bf16x8 Bf = *(const bf16x8*)(w1kt + (size_t)(nt * 16 + m) * 512 + k0);
            acc[0][nt] = __builtin_amdgcn_mfma_f32_16x16x32_bf16(A0, Bf, acc[0][nt], 0, 0, 0);
            acc[1][nt] = __builtin_amdgcn_mfma_f32_16x16x32_bf16(A1, Bf, acc[1][nt], 0, 0, 0);
        }
    }

    // ---- epilogue: score[p] = sum_h relu(C[p][h]+proj[h]) * W2[h] ----
#pragma unroll
    for (int mt = 0; mt < 2; mt++) {
        float p0 = 0.f, p1 = 0.f, p2 = 0.f, p3 = 0.f;
#pragma unroll
        for (int nt = 0; nt < 4; nt++) {
            const int h = nt * 16 + m;
            const float pr = projl[h];
            const float w2v = w2l[h];
            const f32x4 c = acc[mt][nt];
            p0 += fmaxf(c[0] + pr, 0.f) * w2v;
            p1 += fmaxf(c[1] + pr, 0.f) * w2v;
            p2 += fmaxf(c[2] + pr, 0.f) * w2v;
            p3 += fmaxf(c[3] + pr, 0.f) * w2v;
        }
#pragma unroll
        for (int off = 1; off < 16; off <<= 1) {
            p0 += __shfl_xor(p0, off);
            p1 += __shfl_xor(p1, off);
            p2 += __shfl_xor(p2, off);
            p3 += __shfl_xor(p3, off);
        }
        if (m == 0) {
            const int pbase = pw + mt * 16 + q * 4;
            scores[pbase + 0] = p0; scores[pbase + 1] = p1;
            scores[pbase + 2] = p2; scores[pbase + 3] = p3;
        }
    }
    __syncthreads();

    // ---- masked softmax over 128 scores (wave 0), write weights ----
    if (w == 0) {
        const int pa = lane, pb = lane + 64;
        float s0 = (mask[b * 128 + pa] == 0) ? -INFINITY : scores[pa];
        float s1 = (mask[b * 128 + pb] == 0) ? -INFINITY : scores[pb];
        float mx = fmaxf(s0, s1);
#pragma unroll
        for (int off = 32; off; off >>= 1) mx = fmaxf(mx, __shfl_xor(mx, off));
        float e0 = __expf(s0 - mx), e1 = __expf(s1 - mx);
        float sum = e0 + e1;
#pragma unroll
        for (int off = 32; off; off >>= 1) sum += __shfl_xor(sum, off);
        const float inv = 1.0f / sum;
        e0 *= inv; e1 *= inv;
        wts[pa] = e0; wts[pb] = e1;
        float* wout = out + (size_t)NB * 1536;
        wout[b * 128 + pa] = e0;
        wout[b * 128 + pb] = e1;
    }
    __syncthreads();

    // ---- context[k] = sum_p w[p]*keys[p][k]; thread owns cols 2t, 2t+1 ----
    {
        float a0 = 0.f, a1 = 0.f;
        const int c = 2 * t;
#pragma unroll 4
        for (int p = 0; p < 128; p++) {
            const float wv = wts[p];
            const uint32_t uv = *(const uint32_t*)(sk + p * SKLD + c);
            const float f0 = __uint_as_float(uv << 16);
            const float f1 = __uint_as_float(uv & 0xffff0000u);
            a0 += wv * f0;
            a1 += wv * f1;
        }
        out[(size_t)b * 1536 + c] = a0;
        out[(size_t)b * 1536 + c + 1] = a1;
    }
    // ---- frame passthrough: embeddings[:, 512:1536] = frameLSTM_h ----
    {
        const float4 fv = *(const float4*)(frame + (size_t)b * 1024 + t * 4);
        *(float4*)(out + (size_t)b * 1536 + 512 + t * 4) = fv;
    }
}

extern "C" void kernel_launch(void* const* d_in, const int* in_sizes, int n_in,
                              void* d_out, int out_size, void* d_ws, size_t ws_size,
                              hipStream_t stream) {
    const float* query = (const float*)d_in[0];
    const float* keys  = (const float*)d_in[1];
    const float* frame = (const float*)d_in[2];
    const int*   mask  = (const int*)d_in[3];
    const float* W1    = (const float*)d_in[4];
    const float* W2    = (const float*)d_in[5];
    float* out = (float*)d_out;

    // ws layout: [0,64KB) W1kT bf16 [64][512]; [64KB,128KB) proj fp32 [256][64]
    bf16*  w1kt = (bf16*)d_ws;
    float* proj = (float*)((char*)d_ws + 65536);

    hipFuncSetAttribute((const void*)attn_kernel,
                        hipFuncAttributeMaxDynamicSharedMemorySize, SMEM_BYTES);

    prep_kernel<<<272, 256, 0, stream>>>(query, frame, W1, w1kt, proj);
    attn_kernel<<<256, 256, SMEM_BYTES, stream>>>(keys, frame, mask, W2, w1kt, proj, out);
}

// Round 3
// 126.517 us; speedup vs baseline: 1.3328x; 1.1065x over previous
//
#include <hip/hip_runtime.h>
#include <hip/hip_bf16.h>
#include <cstdint>
#include <math.h>

// Shapes: B=256, P=128, K=512, HE=1024, HF=512 (2HF=1024), D=2560, HID=64
// Outputs: embeddings (256,1,1536) then weights (256,128), fp32, flat-concat.

typedef __bf16 bf16;
typedef __attribute__((ext_vector_type(8))) __bf16 bf16x8;
typedef __attribute__((ext_vector_type(4))) __bf16 bf16x4;
typedef __attribute__((ext_vector_type(4))) float f32x4;

#define NB 256
#define NP 128
#define NK 512
#define SKLD 520   // keys LDS row stride in bf16 elems: 520*2B=1040B -> 4-bank shift/row, 2-way alias (free)
#define SK_BYTES (NP * SKLD * 2)                  // 133120
#define SMEM_BYTES (SK_BYTES + 128*4 + 128*4 + 64*4 + 64*4)  // +scores+wts+proj+w2 = 134656

// ---------------- Kernel A: proj GEMV (2 blocks/batch, split-K) + W1k repack ----
// R1 post-mortem: 1 block/batch still ~26us — 512-deep serial FMA chain per
// thread is latency-bound. Now: block=(b,half), each thread chains only 256
// FMAs with 8 loads in flight; partials to ws, attn sums the two halves.
// blocks 0..511  : proj_part[half][b][h]
// blocks 512..527: W1kT[h][k] = bf16(W1[k*64+h]) via LDS transpose
__global__ __launch_bounds__(256) void prep_kernel(
    const float* __restrict__ query, const float* __restrict__ frame,
    const float* __restrict__ W1, bf16* __restrict__ w1kt,
    float* __restrict__ proj_part)
{
    const int blk = blockIdx.x;
    const int t = threadIdx.x;
    if (blk < 512) {
        __shared__ float part[4][64];
        const int b = blk >> 1;
        const int half = blk & 1;            // 0: query d[0,1024), 1: frame d[1024,2048)
        const int h = t & 63;
        const int g = t >> 6;                // 4 chunks of 256 d's
        const float* src = (half == 0 ? query : frame) + (size_t)b * 1024 + g * 256;
        const float* wrow = W1 + (size_t)(512 + half * 1024 + g * 256) * 64 + h;
        float acc = 0.f;
#pragma unroll 8
        for (int dd = 0; dd < 256; dd++)
            acc += src[dd] * wrow[(size_t)dd * 64];
        part[g][h] = acc;
        __syncthreads();
        if (t < 64)
            proj_part[((size_t)half * NB + b) * 64 + t] =
                part[0][t] + part[1][t] + part[2][t] + part[3][t];
    } else {
        // repack: 16 blocks, block j handles k-rows [32j, 32j+32)
        __shared__ float s[32][65];
        const int j = blk - 512;
        const int k0 = j * 32;
#pragma unroll
        for (int i = 0; i < 8; i++) {
            const int idx = t + 256 * i;          // 0..2047
            const int k = idx >> 6, h = idx & 63;
            s[k][h] = W1[(size_t)(k0 + k) * 64 + h];
        }
        __syncthreads();
#pragma unroll
        for (int i = 0; i < 8; i++) {
            const int idx = t + 256 * i;
            const int h = idx >> 5, kk = idx & 31;
            w1kt[(size_t)h * 512 + k0 + kk] = (bf16)s[kk][h];
        }
    }
}

// ---------------- Kernel B: fused attention, one block per batch ----------------
__global__ __launch_bounds__(256) void attn_kernel(
    const float* __restrict__ keys, const float* __restrict__ frame,
    const int* __restrict__ mask, const float* __restrict__ W2,
    const bf16* __restrict__ w1kt, const float* __restrict__ proj_part,
    float* __restrict__ out)
{
    extern __shared__ char smem[];
    bf16* sk       = (bf16*)smem;                       // [128][520] bf16
    float* scores  = (float*)(smem + SK_BYTES);         // [128]
    float* wts     = scores + 128;                      // [128]
    float* projl   = wts + 128;                         // [64]
    float* w2l     = projl + 64;                        // [64]

    const int b = blockIdx.x;
    const int t = threadIdx.x;

    if (t < 64) projl[t] = proj_part[(size_t)b * 64 + t]
                         + proj_part[((size_t)NB + b) * 64 + t];
    else if (t < 128) w2l[t - 64] = W2[t - 64];

    // ---- stage keys[b] (128x512 fp32) -> LDS bf16, coalesced 1KB/wave-instr ----
    const float* kb = keys + (size_t)b * (NP * NK);
    {
        const int rowadd = (t >> 7);          // 0/1
        const int c0 = (t & 127) * 4;
#pragma unroll 8
        for (int i = 0; i < 64; i++) {
            const float4 v = *(const float4*)(kb + (size_t)i * 1024 + t * 4);
            bf16x4 bv;
            bv[0] = (bf16)v.x; bv[1] = (bf16)v.y; bv[2] = (bf16)v.z; bv[3] = (bf16)v.w;
            *(bf16x4*)(sk + (2 * i + rowadd) * SKLD + c0) = bv;
        }
    }
    __syncthreads();

    // ---- GEMM: C[p][h] = keys_bf16 @ W1k_bf16 via mfma_f32_16x16x32_bf16 ----
    // wave w owns p in [32w, 32w+32) (2 M-tiles), all 4 N-tiles (h=0..63)
    const int w = t >> 6;
    const int lane = t & 63;
    const int m = lane & 15;       // A row within tile / B col (h) within tile / C col
    const int q = lane >> 4;       // k-quad; C row = q*4 + reg
    const int pw = w * 32;

    f32x4 acc[2][4];
#pragma unroll
    for (int a = 0; a < 2; a++)
#pragma unroll
        for (int n = 0; n < 4; n++) acc[a][n] = (f32x4){0.f, 0.f, 0.f, 0.f};

    for (int kk = 0; kk < 16; kk++) {
        const int k0 = kk * 32 + q * 8;
        const bf16x8 A0 = *(const bf16x8*)(sk + (pw + m) * SKLD + k0);
        const bf16x8 A1 = *(const bf16x8*)(sk + (pw + 16 + m) * SKLD + k0);
#pragma unroll
        for (int nt = 0; nt < 4; nt++) {
            const bf16x8 Bf = *(const bf16x8*)(w1kt + (size_t)(nt * 16 + m) * 512 + k0);
            acc[0][nt] = __builtin_amdgcn_mfma_f32_16x16x32_bf16(A0, Bf, acc[0][nt], 0, 0, 0);
            acc[1][nt] = __builtin_amdgcn_mfma_f32_16x16x32_bf16(A1, Bf, acc[1][nt], 0, 0, 0);
        }
    }

    // ---- epilogue: score[p] = sum_h relu(C[p][h]+proj[h]) * W2[h] ----
#pragma unroll
    for (int mt = 0; mt < 2; mt++) {
        float p0 = 0.f, p1 = 0.f, p2 = 0.f, p3 = 0.f;
#pragma unroll
        for (int nt = 0; nt < 4; nt++) {
            const int h = nt * 16 + m;
            const float pr = projl[h];
            const float w2v = w2l[h];
            const f32x4 c = acc[mt][nt];
            p0 += fmaxf(c[0] + pr, 0.f) * w2v;
            p1 += fmaxf(c[1] + pr, 0.f) * w2v;
            p2 += fmaxf(c[2] + pr, 0.f) * w2v;
            p3 += fmaxf(c[3] + pr, 0.f) * w2v;
        }
#pragma unroll
        for (int off = 1; off < 16; off <<= 1) {
            p0 += __shfl_xor(p0, off);
            p1 += __shfl_xor(p1, off);
            p2 += __shfl_xor(p2, off);
            p3 += __shfl_xor(p3, off);
        }
        if (m == 0) {
            const int pbase = pw + mt * 16 + q * 4;
            scores[pbase + 0] = p0; scores[pbase + 1] = p1;
            scores[pbase + 2] = p2; scores[pbase + 3] = p3;
        }
    }
    __syncthreads();

    // ---- masked softmax over 128 scores (wave 0), write weights ----
    if (w == 0) {
        const int pa = lane, pb = lane + 64;
        float s0 = (mask[b * 128 + pa] == 0) ? -INFINITY : scores[pa];
        float s1 = (mask[b * 128 + pb] == 0) ? -INFINITY : scores[pb];
        float mx = fmaxf(s0, s1);
#pragma unroll
        for (int off = 32; off; off >>= 1) mx = fmaxf(mx, __shfl_xor(mx, off));
        float e0 = __expf(s0 - mx), e1 = __expf(s1 - mx);
        float sum = e0 + e1;
#pragma unroll
        for (int off = 32; off; off >>= 1) sum += __shfl_xor(sum, off);
        const float inv = 1.0f / sum;
        e0 *= inv; e1 *= inv;
        wts[pa] = e0; wts[pb] = e1;
        float* wout = out + (size_t)NB * 1536;
        wout[b * 128 + pa] = e0;
        wout[b * 128 + pb] = e1;
    }
    __syncthreads();

    // ---- context[k] = sum_p w[p]*keys[p][k]; thread owns cols 2t, 2t+1 ----
    {
        float a0 = 0.f, a1 = 0.f;
        const int c = 2 * t;
#pragma unroll 8
        for (int p = 0; p < 128; p++) {
            const float wv = wts[p];
            const uint32_t uv = *(const uint32_t*)(sk + p * SKLD + c);
            const float f0 = __uint_as_float(uv << 16);
            const float f1 = __uint_as_float(uv & 0xffff0000u);
            a0 += wv * f0;
            a1 += wv * f1;
        }
        out[(size_t)b * 1536 + c] = a0;
        out[(size_t)b * 1536 + c + 1] = a1;
    }
    // ---- frame passthrough: embeddings[:, 512:1536] = frameLSTM_h ----
    {
        const float4 fv = *(const float4*)(frame + (size_t)b * 1024 + t * 4);
        *(float4*)(out + (size_t)b * 1536 + 512 + t * 4) = fv;
    }
}

extern "C" void kernel_launch(void* const* d_in, const int* in_sizes, int n_in,
                              void* d_out, int out_size, void* d_ws, size_t ws_size,
                              hipStream_t stream) {
    const float* query = (const float*)d_in[0];
    const float* keys  = (const float*)d_in[1];
    const float* frame = (const float*)d_in[2];
    const int*   mask  = (const int*)d_in[3];
    const float* W1    = (const float*)d_in[4];
    const float* W2    = (const float*)d_in[5];
    float* out = (float*)d_out;

    // ws layout: [0,64KB) W1kT bf16 [64][512]; [64KB,192KB) proj_part fp32 [2][256][64]
    bf16*  w1kt      = (bf16*)d_ws;
    float* proj_part = (float*)((char*)d_ws + 65536);

    hipFuncSetAttribute((const void*)attn_kernel,
                        hipFuncAttributeMaxDynamicSharedMemorySize, SMEM_BYTES);

    prep_kernel<<<528, 256, 0, stream>>>(query, frame, W1, w1kt, proj_part);
    attn_kernel<<<256, 256, SMEM_BYTES, stream>>>(keys, frame, mask, W2, w1kt, proj_part, out);
}